// Round 3
// baseline (487.515 us; speedup 1.0000x reference)
//
#include <hip/hip_runtime.h>
#include <hip/hip_bf16.h>

// Dims fixed by the reference
#define BB 8
#define NN 2048
#define DF 256
#define HH 64

using bf16x8 = __attribute__((ext_vector_type(8))) short;
using f32x4  = __attribute__((ext_vector_type(4))) float;
typedef unsigned short u16;

static __device__ __forceinline__ short bf_hi_bits(float v, float* hi_f) {
    __hip_bfloat16 h = __float2bfloat16(v);
    *hi_f = __bfloat162float(h);
    return __builtin_bit_cast(short, h);
}

// ---------------------------------------------------------------------------
// Kernel 0: pre-split W (fp32) into MFMA B-fragment order, split bf16 (hi,lo).
// B-operand layout (mfma_f32_16x16x32_bf16): lane l holds
// B[k = (l>>4)*8 + j][n = l&15]. Buffer: [kc(8)][ct(8)][p(hi/lo)][lane(64)][8]
// ct 0..3 -> Wq cols, ct 4..7 -> Wk. Wsp aliases the START of the pi output
// (written here, read by qk_mfma, overwritten later by attn -> stream-safe).
// ---------------------------------------------------------------------------
__global__ __launch_bounds__(64) void wprep_kernel(
    const float* __restrict__ Wq, const float* __restrict__ Wk,
    u16* __restrict__ Wsp)
{
    const int fid  = blockIdx.x;          // kc*8 + ct
    const int kc   = fid >> 3, ct = fid & 7;
    const int lane = threadIdx.x;
    const float* W = (ct < 4) ? Wq : Wk;
    const int col  = (ct & 3) * 16 + (lane & 15);
    const int krow = kc * 32 + (lane >> 4) * 8;
    bf16x8 hv, lv;
#pragma unroll
    for (int j = 0; j < 8; ++j) {
        float w = W[(size_t)(krow + j) * HH + col];
        float hf, d;
        hv[j] = bf_hi_bits(w, &hf);
        lv[j] = bf_hi_bits(w - hf, &d);
    }
    u16* dst = Wsp + (size_t)fid * 1024 + lane * 8;
    *(bf16x8*)dst         = hv;
    *(bf16x8*)(dst + 512) = lv;
}

// ---------------------------------------------------------------------------
// Kernel 1: Q/K projection via split-bf16 MFMA (proven in round 2).
// ---------------------------------------------------------------------------
__global__ __launch_bounds__(64) void qk_mfma_kernel(
    const float* __restrict__ f, const float* __restrict__ log_eps,
    const float* __restrict__ Wq, const float* __restrict__ Wk,
    const u16* __restrict__ Wsp,
    __hip_bfloat16* __restrict__ Qs, __hip_bfloat16* __restrict__ Ks)
{
    const int lane = threadIdx.x;
    const int l15  = lane & 15, quad = lane >> 4;
    const int row0 = blockIdx.x * 16;
    const int b    = row0 >> 11;

    f32x4 acc[8] = {};
    const float* frow = f + (size_t)(row0 + l15) * DF + quad * 8;

#pragma unroll
    for (int kc = 0; kc < 8; ++kc) {
        float4 a0 = *(const float4*)(frow + kc * 32);
        float4 a1 = *(const float4*)(frow + kc * 32 + 4);
        bf16x8 ah, al;
#pragma unroll
        for (int e = 0; e < 4; ++e) {
            float hf, d;
            float v0 = (&a0.x)[e], v1 = (&a1.x)[e];
            ah[e]     = bf_hi_bits(v0, &hf);
            al[e]     = bf_hi_bits(v0 - hf, &d);
            ah[e + 4] = bf_hi_bits(v1, &hf);
            al[e + 4] = bf_hi_bits(v1 - hf, &d);
        }
        const u16* wb = Wsp + (size_t)kc * 8192 + lane * 8;
#pragma unroll
        for (int ct = 0; ct < 8; ++ct) {
            bf16x8 bh = *(const bf16x8*)(wb + ct * 1024);
            bf16x8 bl = *(const bf16x8*)(wb + ct * 1024 + 512);
            acc[ct] = __builtin_amdgcn_mfma_f32_16x16x32_bf16(ah, bh, acc[ct], 0, 0, 0);
            acc[ct] = __builtin_amdgcn_mfma_f32_16x16x32_bf16(ah, bl, acc[ct], 0, 0, 0);
            acc[ct] = __builtin_amdgcn_mfma_f32_16x16x32_bf16(al, bh, acc[ct], 0, 0, 0);
        }
    }

    const float le = log_eps[b];
#pragma unroll
    for (int ct = 0; ct < 8; ++ct) {
        const int h = (ct & 3) * 16 + l15;
        const float wlast = (ct < 4 ? Wq : Wk)[DF * HH + h];
        __hip_bfloat16* out = (ct < 4) ? Qs : Ks;
        const float sc = (ct < 4) ? 0.125f : 1.0f;
#pragma unroll
        for (int r = 0; r < 4; ++r) {
            int bn = row0 + quad * 4 + r;
            float v = (acc[ct][r] + le * wlast) * sc;
            __hip_bfloat16 hi = __float2bfloat16(v);
            __hip_bfloat16 lo = __float2bfloat16(v - __bfloat162float(hi));
            out[(size_t)bn * 128 + h]      = hi;
            out[(size_t)bn * 128 + 64 + h] = lo;
        }
    }
}

// ---------------------------------------------------------------------------
// Kernel 2: fused attention, 2 total N^2 passes (round-0 structure) with:
//  - 1-D grid, b = bid&7  -> XCD-batch affinity (per-XCD L2 set = 1 MB, hot)
//  - 512-thread blocks (8 waves): 16 waves/CU at 2 blocks/CU
//  - software-pipelined A-fragment loads (static double buffer)
//  - colsum cross-quad shuffles deferred out of the inner loop
//  - non-temporal pi stores (don't evict Q/K from L2)
// ---------------------------------------------------------------------------
__global__ __launch_bounds__(512, 4) void attn_kernel(
    const u16* __restrict__ Qs, const u16* __restrict__ Ks,
    const float* __restrict__ x, float* __restrict__ y, float* __restrict__ pi)
{
    __shared__ float xs[NN * 3];             // 24 KB: x for this batch
    __shared__ float cred[32];
    __shared__ float yred[8 * 2 * 16 * 3];   // [wave][ct][col16][d]

    const int tid   = threadIdx.x;
    const int bid   = blockIdx.x;
    const int b     = bid & 7;               // XCD affinity (round-robin %8)
    const int strip = bid >> 3;
    const int m0    = strip * 32;
    const int wave  = tid >> 6;              // 0..7
    const int lane  = tid & 63;
    const int l15   = lane & 15;
    const int quad  = lane >> 4;

    if (tid < 32) cred[tid] = 0.f;
    for (int i = tid; i < NN * 3; i += 512) xs[i] = x[(size_t)b * NN * 3 + i];
    __syncthreads();

    // K strip B-fragments, resident all kernel
    bf16x8 bh[2][2], bl[2][2];
    {
        const u16* Kb = Ks + ((size_t)b * NN + m0) * 128;
#pragma unroll
        for (int ct = 0; ct < 2; ++ct) {
            const u16* kr = Kb + (size_t)(ct * 16 + l15) * 128;
#pragma unroll
            for (int ks = 0; ks < 2; ++ks) {
                int k0 = ks * 32 + quad * 8;
                bh[ct][ks] = *(const bf16x8*)(kr + k0);
                bl[ct][ks] = *(const bf16x8*)(kr + 64 + k0);
            }
        }
    }

    const u16* Qb = Qs + (size_t)b * NN * 128;

    // iteration -> row: it in [0,16): row0 = (it>>1)*256 + wave*32 + (it&1)*16
#define ROWOF(it) ((((it) >> 1) << 8) + wave * 32 + (((it) & 1) << 4))

#define LOADQ(AH, AL, row0)                                                    \
    {                                                                          \
        const u16* qr = Qb + (size_t)((row0) + l15) * 128;                     \
        _Pragma("unroll")                                                      \
        for (int ks = 0; ks < 2; ++ks) {                                       \
            int k0 = ks * 32 + quad * 8;                                       \
            AH[ks] = *(const bf16x8*)(qr + k0);                                \
            AL[ks] = *(const bf16x8*)(qr + 64 + k0);                           \
        }                                                                      \
    }

#define QKMFMA(ACC, AH, AL, CT)                                                \
    {                                                                          \
        _Pragma("unroll")                                                      \
        for (int ks = 0; ks < 2; ++ks) {                                       \
            ACC = __builtin_amdgcn_mfma_f32_16x16x32_bf16(AH[ks], bh[CT][ks], ACC, 0, 0, 0); \
            ACC = __builtin_amdgcn_mfma_f32_16x16x32_bf16(AH[ks], bl[CT][ks], ACC, 0, 0, 0); \
            ACC = __builtin_amdgcn_mfma_f32_16x16x32_bf16(AL[ks], bh[CT][ks], ACC, 0, 0, 0); \
        }                                                                      \
    }

    float cs0 = 0.f, cs1 = 0.f;
    float yacc[2][3] = {{0.f, 0.f, 0.f}, {0.f, 0.f, 0.f}};

    // ---- Pass 1: column sums + y accumulation, pipelined ----
#define P1BODY(it, AH, AL)                                                     \
    {                                                                          \
        const int row0 = ROWOF(it);                                            \
        float xv[4][3];                                                        \
        _Pragma("unroll")                                                      \
        for (int r = 0; r < 4; ++r) {                                          \
            int row = row0 + quad * 4 + r;                                     \
            xv[r][0] = xs[row * 3 + 0];                                        \
            xv[r][1] = xs[row * 3 + 1];                                        \
            xv[r][2] = xs[row * 3 + 2];                                        \
        }                                                                      \
        _Pragma("unroll")                                                      \
        for (int ct = 0; ct < 2; ++ct) {                                       \
            f32x4 acc = {0.f, 0.f, 0.f, 0.f};                                  \
            QKMFMA(acc, AH, AL, ct);                                           \
            float s = 0.f;                                                     \
            _Pragma("unroll")                                                  \
            for (int r = 0; r < 4; ++r) {                                      \
                float v = __expf(acc[r]);                                      \
                s += v;                                                        \
                yacc[ct][0] = fmaf(v, xv[r][0], yacc[ct][0]);                  \
                yacc[ct][1] = fmaf(v, xv[r][1], yacc[ct][1]);                  \
                yacc[ct][2] = fmaf(v, xv[r][2], yacc[ct][2]);                  \
            }                                                                  \
            if (ct == 0) cs0 += s; else cs1 += s;                              \
        }                                                                      \
    }

    {
        bf16x8 ahA[2], alA[2], ahB[2], alB[2];
        LOADQ(ahA, alA, ROWOF(0));
        for (int it = 0; it < 16; it += 2) {
            LOADQ(ahB, alB, ROWOF(it + 1));
            P1BODY(it, ahA, alA);
            if (it + 2 < 16) LOADQ(ahA, alA, ROWOF(it + 2));
            P1BODY(it + 1, ahB, alB);
        }
    }

    // deferred cross-quad reduction for colsums
    cs0 += __shfl_xor(cs0, 16); cs0 += __shfl_xor(cs0, 32);
    cs1 += __shfl_xor(cs1, 16); cs1 += __shfl_xor(cs1, 32);
    if (quad == 0) {
        atomicAdd(&cred[l15],      cs0);
        atomicAdd(&cred[16 + l15], cs1);
    }
#pragma unroll
    for (int ct = 0; ct < 2; ++ct)
#pragma unroll
        for (int d = 0; d < 3; ++d) {
            yacc[ct][d] += __shfl_xor(yacc[ct][d], 16);
            yacc[ct][d] += __shfl_xor(yacc[ct][d], 32);
        }
    if (quad == 0) {
#pragma unroll
        for (int ct = 0; ct < 2; ++ct)
#pragma unroll
            for (int d = 0; d < 3; ++d)
                yred[((wave * 2 + ct) * 16 + l15) * 3 + d] = yacc[ct][d];
    }
    __syncthreads();

    if (tid < 96) {                          // y[m,d] = (sum exp*x) / colsum
        int c = tid / 3, d = tid - c * 3;
        int ct = c >> 4, cl = c & 15;
        float s = 0.f;
#pragma unroll
        for (int w = 0; w < 8; ++w)
            s += yred[((w * 2 + ct) * 16 + cl) * 3 + d];
        y[((size_t)b * NN + m0 + c) * 3 + d] = s / cred[c];
    }

    const float invN = 1.0f / (float)NN;
    const float iv0  = invN / cred[l15];
    const float iv1  = invN / cred[16 + l15];
    float* pib = pi + (size_t)b * NN * NN + m0;

    // ---- Pass 2: recompute, write pi (non-temporal), pipelined ----
#define P2BODY(it, AH, AL)                                                     \
    {                                                                          \
        const int row0 = ROWOF(it);                                            \
        _Pragma("unroll")                                                      \
        for (int ct = 0; ct < 2; ++ct) {                                       \
            f32x4 acc = {0.f, 0.f, 0.f, 0.f};                                  \
            QKMFMA(acc, AH, AL, ct);                                           \
            const float iv = (ct == 0) ? iv0 : iv1;                            \
            float* op = pib + (size_t)(row0 + quad * 4) * NN + ct * 16 + l15;  \
            _Pragma("unroll")                                                  \
            for (int r = 0; r < 4; ++r)                                        \
                __builtin_nontemporal_store(__expf(acc[r]) * iv,               \
                                            op + (size_t)r * NN);              \
        }                                                                      \
    }

    {
        bf16x8 ahA[2], alA[2], ahB[2], alB[2];
        LOADQ(ahA, alA, ROWOF(0));
        for (int it = 0; it < 16; it += 2) {
            LOADQ(ahB, alB, ROWOF(it + 1));
            P2BODY(it, ahA, alA);
            if (it + 2 < 16) LOADQ(ahA, alA, ROWOF(it + 2));
            P2BODY(it + 1, ahB, alB);
        }
    }
#undef ROWOF
#undef LOADQ
#undef QKMFMA
#undef P1BODY
#undef P2BODY
}

// ---------------------------------------------------------------------------
extern "C" void kernel_launch(void* const* d_in, const int* in_sizes, int n_in,
                              void* d_out, int out_size, void* d_ws, size_t ws_size,
                              hipStream_t stream) {
    const float* f  = (const float*)d_in[0];
    const float* x  = (const float*)d_in[1];
    const float* le = (const float*)d_in[2];
    const float* Wq = (const float*)d_in[3];
    const float* Wk = (const float*)d_in[4];

    float* y  = (float*)d_out;                       // (B, N, 3)
    float* pi = (float*)d_out + (size_t)BB * NN * 3; // (B, N, N)

    // Workspace: exactly the proven 8 MB (split-bf16 Q and K). The 128 KB
    // W-fragment table temporally aliases the pi output buffer.
    __hip_bfloat16* Qs = (__hip_bfloat16*)d_ws;      // 4 MB
    __hip_bfloat16* Ks = Qs + (size_t)BB * NN * 128; // 4 MB
    u16* Wsp = (u16*)pi;                             // 128 KB, stream-ordered alias

    wprep_kernel<<<dim3(64), 64, 0, stream>>>(Wq, Wk, Wsp);
    qk_mfma_kernel<<<dim3(BB * NN / 16), 64, 0, stream>>>(f, le, Wq, Wk, Wsp, Qs, Ks);
    attn_kernel<<<dim3(512), 512, 0, stream>>>((const u16*)Qs, (const u16*)Ks,
                                               x, y, pi);
}

// Round 4
// 195.113 us; speedup vs baseline: 2.4986x; 2.4986x over previous
//
#include <hip/hip_runtime.h>
#include <hip/hip_bf16.h>

// Dims fixed by the reference
#define BB 8
#define NN 2048
#define DF 256
#define HH 64

using bf16x8 = __attribute__((ext_vector_type(8))) short;
using f32x4  = __attribute__((ext_vector_type(4))) float;
typedef unsigned short u16;

static __device__ __forceinline__ short bf_hi_bits(float v, float* hi_f) {
    __hip_bfloat16 h = __float2bfloat16(v);
    *hi_f = __bfloat162float(h);
    return __builtin_bit_cast(short, h);
}

// ---------------------------------------------------------------------------
// Kernel 0: pre-split W (fp32) into MFMA B-fragment order, split bf16 (hi,lo).
// B-operand layout (mfma_f32_16x16x32_bf16): lane l holds
// B[k = (l>>4)*8 + j][n = l&15]. Buffer: [kc(8)][ct(8)][p(hi/lo)][lane(64)][8]
// ct 0..3 -> Wq cols, ct 4..7 -> Wk. Wsp aliases the START of the pi output
// (written here, read by qk_mfma, overwritten later by attn -> stream-safe).
// ---------------------------------------------------------------------------
__global__ __launch_bounds__(64) void wprep_kernel(
    const float* __restrict__ Wq, const float* __restrict__ Wk,
    u16* __restrict__ Wsp)
{
    const int fid  = blockIdx.x;          // kc*8 + ct
    const int kc   = fid >> 3, ct = fid & 7;
    const int lane = threadIdx.x;
    const float* W = (ct < 4) ? Wq : Wk;
    const int col  = (ct & 3) * 16 + (lane & 15);
    const int krow = kc * 32 + (lane >> 4) * 8;
    bf16x8 hv, lv;
#pragma unroll
    for (int j = 0; j < 8; ++j) {
        float w = W[(size_t)(krow + j) * HH + col];
        float hf, d;
        hv[j] = bf_hi_bits(w, &hf);
        lv[j] = bf_hi_bits(w - hf, &d);
    }
    u16* dst = Wsp + (size_t)fid * 1024 + lane * 8;
    *(bf16x8*)dst         = hv;
    *(bf16x8*)(dst + 512) = lv;
}

// ---------------------------------------------------------------------------
// Kernel 1: Q/K projection via split-bf16 MFMA, kc-split across 4 waves.
// Block = 16 rows, 256 threads. Wave w handles K-slices kc = {2w, 2w+1};
// partial accumulators reduced through LDS; wave 0 does the epilogue.
// 1024 blocks x 4 waves = 16 waves/CU (vs 4 before), serial chain 4x shorter.
// ---------------------------------------------------------------------------
__global__ __launch_bounds__(256) void qk_mfma_kernel(
    const float* __restrict__ f, const float* __restrict__ log_eps,
    const float* __restrict__ Wq, const float* __restrict__ Wk,
    const u16* __restrict__ Wsp,
    __hip_bfloat16* __restrict__ Qs, __hip_bfloat16* __restrict__ Ks)
{
    __shared__ f32x4 red[3 * 64 * 8];     // 24 KB: waves 1..3 partial accs

    const int tid  = threadIdx.x;
    const int wave = tid >> 6;
    const int lane = tid & 63;
    const int l15  = lane & 15, quad = lane >> 4;
    const int row0 = blockIdx.x * 16;
    const int b    = row0 >> 11;          // 16-row blocks never straddle batch

    f32x4 acc[8] = {};
    const float* frow = f + (size_t)(row0 + l15) * DF + quad * 8;

#pragma unroll
    for (int kci = 0; kci < 2; ++kci) {
        const int kc = wave * 2 + kci;
        // A-fragment: row = l15, k = quad*8 + j (fp32 -> split bf16)
        float4 a0 = *(const float4*)(frow + kc * 32);
        float4 a1 = *(const float4*)(frow + kc * 32 + 4);
        bf16x8 ah, al;
#pragma unroll
        for (int e = 0; e < 4; ++e) {
            float hf, d;
            float v0 = (&a0.x)[e], v1 = (&a1.x)[e];
            ah[e]     = bf_hi_bits(v0, &hf);
            al[e]     = bf_hi_bits(v0 - hf, &d);
            ah[e + 4] = bf_hi_bits(v1, &hf);
            al[e + 4] = bf_hi_bits(v1 - hf, &d);
        }
        const u16* wb = Wsp + (size_t)kc * 8192 + lane * 8;
#pragma unroll
        for (int ct = 0; ct < 8; ++ct) {
            bf16x8 bh = *(const bf16x8*)(wb + ct * 1024);
            bf16x8 bl = *(const bf16x8*)(wb + ct * 1024 + 512);
            acc[ct] = __builtin_amdgcn_mfma_f32_16x16x32_bf16(ah, bh, acc[ct], 0, 0, 0);
            acc[ct] = __builtin_amdgcn_mfma_f32_16x16x32_bf16(ah, bl, acc[ct], 0, 0, 0);
            acc[ct] = __builtin_amdgcn_mfma_f32_16x16x32_bf16(al, bh, acc[ct], 0, 0, 0);
        }
    }

    if (wave > 0) {
#pragma unroll
        for (int ct = 0; ct < 8; ++ct)
            red[((wave - 1) * 64 + lane) * 8 + ct] = acc[ct];
    }
    __syncthreads();
    if (wave != 0) return;

#pragma unroll
    for (int ct = 0; ct < 8; ++ct)
#pragma unroll
        for (int w = 0; w < 3; ++w) {
            f32x4 p = red[(w * 64 + lane) * 8 + ct];
            acc[ct][0] += p[0]; acc[ct][1] += p[1];
            acc[ct][2] += p[2]; acc[ct][3] += p[3];
        }

    const float le = log_eps[b];
#pragma unroll
    for (int ct = 0; ct < 8; ++ct) {
        const int h = (ct & 3) * 16 + l15;
        const float wlast = (ct < 4 ? Wq : Wk)[DF * HH + h];
        __hip_bfloat16* out = (ct < 4) ? Qs : Ks;
        const float sc = (ct < 4) ? 0.125f : 1.0f;
#pragma unroll
        for (int r = 0; r < 4; ++r) {
            int bn = row0 + quad * 4 + r;     // C/D: col=l15, row=quad*4+r
            float v = (acc[ct][r] + le * wlast) * sc;
            __hip_bfloat16 hi = __float2bfloat16(v);
            __hip_bfloat16 lo = __float2bfloat16(v - __bfloat162float(hi));
            out[(size_t)bn * 128 + h]      = hi;
            out[(size_t)bn * 128 + 64 + h] = lo;
        }
    }
}

// ---------------------------------------------------------------------------
// Kernel 2: fused attention, proven round-0 2-pass structure, widened to
// 64-column strips (4 col-tiles resident in registers) with 512-thread
// blocks. Q-fragment re-read traffic halves (the measured 6.4 TB/s wall):
// 256 MB -> 128 MB per pass. Plain stores for pi (L2 write-back coalesces
// the scattered 64 B segments into full lines; round-3 proved non-temporal
// stores cause 5x write amplification here). Grid (32, 8) = 256 blocks,
// 8 waves each = 2048 waves (same as round 0).
// ---------------------------------------------------------------------------
__global__ __launch_bounds__(512, 2) void attn_kernel(
    const u16* __restrict__ Qs, const u16* __restrict__ Ks,
    const float* __restrict__ x, float* __restrict__ y, float* __restrict__ pi)
{
    __shared__ float xs[NN * 3];             // 24 KB: x for this batch
    __shared__ float cred[64];               // strip colsums
    __shared__ float yred[8 * 4 * 16 * 3];   // [wave][ct][col16][d], 6 KB

    const int tid   = threadIdx.x;
    const int strip = blockIdx.x;            // 0..31
    const int b     = blockIdx.y;            // 0..7
    const int m0    = strip * 64;
    const int wave  = tid >> 6;              // 0..7
    const int lane  = tid & 63;
    const int l15   = lane & 15;
    const int quad  = lane >> 4;

    if (tid < 64) cred[tid] = 0.f;
    for (int i = tid; i < NN * 3; i += 512) xs[i] = x[(size_t)b * NN * 3 + i];
    __syncthreads();

    // K-strip B-fragments (4 col-tiles), resident all kernel (~64 VGPR)
    bf16x8 bh[4][2], bl[4][2];
    {
        const u16* Kb = Ks + ((size_t)b * NN + m0) * 128;
#pragma unroll
        for (int ct = 0; ct < 4; ++ct) {
            const u16* kr = Kb + (size_t)(ct * 16 + l15) * 128;
#pragma unroll
            for (int ks = 0; ks < 2; ++ks) {
                int k0 = ks * 32 + quad * 8;
                bh[ct][ks] = *(const bf16x8*)(kr + k0);
                bl[ct][ks] = *(const bf16x8*)(kr + 64 + k0);
            }
        }
    }

    const u16* Qb = Qs + (size_t)b * NN * 128;
    float cs[4] = {0.f, 0.f, 0.f, 0.f};
    float yacc[4][3] = {};

    // ---- Pass 1: column sums + y accumulation ----
    for (int rt = 0; rt < 8; ++rt) {
#pragma unroll
        for (int sr = 0; sr < 2; ++sr) {
            const int row0 = rt * 256 + wave * 32 + sr * 16;
            const u16* qr = Qb + (size_t)(row0 + l15) * 128;
            bf16x8 ah[2], al[2];
#pragma unroll
            for (int ks = 0; ks < 2; ++ks) {
                int k0 = ks * 32 + quad * 8;
                ah[ks] = *(const bf16x8*)(qr + k0);
                al[ks] = *(const bf16x8*)(qr + 64 + k0);
            }
            float xv[4][3];
#pragma unroll
            for (int r = 0; r < 4; ++r) {
                int row = row0 + quad * 4 + r;
                xv[r][0] = xs[row * 3 + 0];
                xv[r][1] = xs[row * 3 + 1];
                xv[r][2] = xs[row * 3 + 2];
            }
#pragma unroll
            for (int ct = 0; ct < 4; ++ct) {
                f32x4 acc = {0.f, 0.f, 0.f, 0.f};
#pragma unroll
                for (int ks = 0; ks < 2; ++ks) {
                    acc = __builtin_amdgcn_mfma_f32_16x16x32_bf16(ah[ks], bh[ct][ks], acc, 0, 0, 0);
                    acc = __builtin_amdgcn_mfma_f32_16x16x32_bf16(ah[ks], bl[ct][ks], acc, 0, 0, 0);
                    acc = __builtin_amdgcn_mfma_f32_16x16x32_bf16(al[ks], bh[ct][ks], acc, 0, 0, 0);
                }
                float s = 0.f;
#pragma unroll
                for (int r = 0; r < 4; ++r) {
                    float v = __expf(acc[r]);
                    s += v;
                    yacc[ct][0] = fmaf(v, xv[r][0], yacc[ct][0]);
                    yacc[ct][1] = fmaf(v, xv[r][1], yacc[ct][1]);
                    yacc[ct][2] = fmaf(v, xv[r][2], yacc[ct][2]);
                }
                cs[ct] += s;
            }
        }
    }

    // deferred cross-quad reductions, then LDS
#pragma unroll
    for (int ct = 0; ct < 4; ++ct) {
        cs[ct] += __shfl_xor(cs[ct], 16);
        cs[ct] += __shfl_xor(cs[ct], 32);
#pragma unroll
        for (int d = 0; d < 3; ++d) {
            yacc[ct][d] += __shfl_xor(yacc[ct][d], 16);
            yacc[ct][d] += __shfl_xor(yacc[ct][d], 32);
        }
    }
    if (quad == 0) {
#pragma unroll
        for (int ct = 0; ct < 4; ++ct) {
            atomicAdd(&cred[ct * 16 + l15], cs[ct]);
#pragma unroll
            for (int d = 0; d < 3; ++d)
                yred[((wave * 4 + ct) * 16 + l15) * 3 + d] = yacc[ct][d];
        }
    }
    __syncthreads();

    if (tid < 192) {                         // 64 cols x 3 dims
        int c = tid / 3, d = tid - c * 3;
        int ct = c >> 4, cl = c & 15;
        float s = 0.f;
#pragma unroll
        for (int w = 0; w < 8; ++w)
            s += yred[((w * 4 + ct) * 16 + cl) * 3 + d];
        y[((size_t)b * NN + m0 + c) * 3 + d] = s / cred[c];
    }

    const float invN = 1.0f / (float)NN;
    float iv[4];
#pragma unroll
    for (int ct = 0; ct < 4; ++ct) iv[ct] = invN / cred[ct * 16 + l15];
    float* pib = pi + (size_t)b * NN * NN + m0;

    // ---- Pass 2: recompute, write pi (plain stores -> L2 coalesces) ----
    for (int rt = 0; rt < 8; ++rt) {
#pragma unroll
        for (int sr = 0; sr < 2; ++sr) {
            const int row0 = rt * 256 + wave * 32 + sr * 16;
            const u16* qr = Qb + (size_t)(row0 + l15) * 128;
            bf16x8 ah[2], al[2];
#pragma unroll
            for (int ks = 0; ks < 2; ++ks) {
                int k0 = ks * 32 + quad * 8;
                ah[ks] = *(const bf16x8*)(qr + k0);
                al[ks] = *(const bf16x8*)(qr + 64 + k0);
            }
#pragma unroll
            for (int ct = 0; ct < 4; ++ct) {
                f32x4 acc = {0.f, 0.f, 0.f, 0.f};
#pragma unroll
                for (int ks = 0; ks < 2; ++ks) {
                    acc = __builtin_amdgcn_mfma_f32_16x16x32_bf16(ah[ks], bh[ct][ks], acc, 0, 0, 0);
                    acc = __builtin_amdgcn_mfma_f32_16x16x32_bf16(ah[ks], bl[ct][ks], acc, 0, 0, 0);
                    acc = __builtin_amdgcn_mfma_f32_16x16x32_bf16(al[ks], bh[ct][ks], acc, 0, 0, 0);
                }
                float* op = pib + (size_t)(row0 + quad * 4) * NN + ct * 16 + l15;
#pragma unroll
                for (int r = 0; r < 4; ++r)
                    op[(size_t)r * NN] = __expf(acc[r]) * iv[ct];
            }
        }
    }
}

// ---------------------------------------------------------------------------
extern "C" void kernel_launch(void* const* d_in, const int* in_sizes, int n_in,
                              void* d_out, int out_size, void* d_ws, size_t ws_size,
                              hipStream_t stream) {
    const float* f  = (const float*)d_in[0];
    const float* x  = (const float*)d_in[1];
    const float* le = (const float*)d_in[2];
    const float* Wq = (const float*)d_in[3];
    const float* Wk = (const float*)d_in[4];

    float* y  = (float*)d_out;                       // (B, N, 3)
    float* pi = (float*)d_out + (size_t)BB * NN * 3; // (B, N, N)

    // Workspace: exactly the proven 8 MB (split-bf16 Q and K). The 128 KB
    // W-fragment table temporally aliases the pi output buffer.
    __hip_bfloat16* Qs = (__hip_bfloat16*)d_ws;      // 4 MB
    __hip_bfloat16* Ks = Qs + (size_t)BB * NN * 128; // 4 MB
    u16* Wsp = (u16*)pi;                             // 128 KB, stream-ordered alias

    wprep_kernel<<<dim3(64), 64, 0, stream>>>(Wq, Wk, Wsp);
    qk_mfma_kernel<<<dim3(BB * NN / 16), 256, 0, stream>>>(f, le, Wq, Wk, Wsp, Qs, Ks);
    attn_kernel<<<dim3(32, BB), 512, 0, stream>>>((const u16*)Qs, (const u16*)Ks,
                                                  x, y, pi);
}